// Round 18
// baseline (273.677 us; speedup 1.0000x reference)
//
#include <hip/hip_runtime.h>
#include <hip/hip_bf16.h>
#include <cstddef>

#define B_ 4
#define N_ 20000
#define P_ 128
#define K_ 128
#define E_ 160000

constexpr int NCH_S = 79;   // ceil(N/256) split-K chunks for spectral projection
constexpr int NSCB  = 79;   // ceil(N/256) scan blocks

typedef __attribute__((ext_vector_type(8))) short short8;
typedef __attribute__((ext_vector_type(4))) float f32x4;

__device__ __forceinline__ unsigned pk2(float x, float y) {
  __hip_bfloat162 h = __float22bfloat162_rn(make_float2(x, y));  // RNE pack
  union { __hip_bfloat162 h; unsigned u; } c; c.h = h; return c.u;
}
__device__ __forceinline__ float bf2f(short s) {
  union { unsigned u; float f; } c; c.u = ((unsigned)(unsigned short)s) << 16; return c.f;
}
__device__ __forceinline__ short f2bs(float x) {
  union { __hip_bfloat16 h; short s; } c; c.h = __float2bfloat16(x); return c.s;
}

// ---------------------------------------------------------------------------
// prep: transpose+scale+bf16.  evT[b][k][n] = bf16(ev[b][n][k]*area[b][n]),
//       xT[b][p][n] = bf16(x[b][n][p]).   grid (ceil(N/64), 2half*2mat, B)
// ---------------------------------------------------------------------------
__global__ __launch_bounds__(256)
void k_prep(const float* __restrict__ ev, const float* __restrict__ xin,
            const float* __restrict__ areas,
            __hip_bfloat16* __restrict__ evT, __hip_bfloat16* __restrict__ xT)
{
  const int tn = blockIdx.x, half = blockIdx.y & 1, mat = blockIdx.y >> 1;
  const int b = blockIdx.z, t = threadIdx.x;
  const int n0 = tn * 64, c0 = half * 64;
  __shared__ float ld[64][65];
  const float* src = (mat ? xin : ev) + (size_t)b * N_ * 128;
  const float* ab  = areas + (size_t)b * N_;
#pragma unroll
  for (int i = 0; i < 4; ++i) {
    int gid = t + i * 256;
    int r = gid >> 4, c4 = (gid & 15) << 2;
    int n = n0 + r;
    float4 v = make_float4(0.f, 0.f, 0.f, 0.f);
    if (n < N_) {
      v = *(const float4*)(src + (size_t)n * 128 + c0 + c4);
      if (mat == 0) { float ar = ab[n]; v.x *= ar; v.y *= ar; v.z *= ar; v.w *= ar; }
    }
    ld[r][c4] = v.x; ld[r][c4+1] = v.y; ld[r][c4+2] = v.z; ld[r][c4+3] = v.w;
  }
  __syncthreads();
  __hip_bfloat16* dst = (mat ? xT : evT) + (size_t)b * 128 * N_;
#pragma unroll
  for (int i = 0; i < 4; ++i) {
    int gid = t + i * 256;
    int cr = gid >> 4, nq = (gid & 15) << 2;
    int n = n0 + nq;
    if (n + 4 <= N_) {                      // N%4==0: never a partial quad
      uint2 u;
      u.x = pk2(ld[nq][cr],   ld[nq+1][cr]);
      u.y = pk2(ld[nq+2][cr], ld[nq+3][cr]);
      *(uint2*)(dst + (size_t)(c0 + cr) * N_ + n) = u;
    }
  }
}

// ---------------------------------------------------------------------------
// W-fragment preps: frag[gg*128+rr] = bf16x8 of W[rr][koff+gg*8 .. +7]
// ---------------------------------------------------------------------------
__global__ __launch_bounds__(256)
void k_wprep(const float* __restrict__ Bre, const float* __restrict__ Bim,
             uint4* __restrict__ WfRe, uint4* __restrict__ WfIm)
{
  int fid = blockIdx.x * 256 + threadIdx.x;
  if (fid >= 2048) return;
  int gg = fid >> 7, rr = fid & 127;
  const float* s0 = Bre + rr * 128 + gg * 8;
  const float* s1 = Bim + rr * 128 + gg * 8;
  float4 a0 = *(const float4*)s0, a1 = *(const float4*)(s0 + 4);
  uint4 u; u.x = pk2(a0.x, a0.y); u.y = pk2(a0.z, a0.w);
  u.z = pk2(a1.x, a1.y); u.w = pk2(a1.z, a1.w);
  WfRe[fid] = u;
  float4 b0 = *(const float4*)s1, b1 = *(const float4*)(s1 + 4);
  uint4 v; v.x = pk2(b0.x, b0.y); v.y = pk2(b0.z, b0.w);
  v.z = pk2(b1.x, b1.y); v.w = pk2(b1.z, b1.w);
  WfIm[fid] = v;
}

// W1 (3 chunks of 128 cols, ldw=384), W2, W3 (ldw=128) -> 5 jobs x 2048 frags
__global__ __launch_bounds__(256)
void k_wprep_mlp(const float* __restrict__ W1, const float* __restrict__ W2,
                 const float* __restrict__ W3, uint4* __restrict__ W1f,
                 uint4* __restrict__ W2f, uint4* __restrict__ W3f)
{
  int fid = blockIdx.x * 256 + threadIdx.x;
  if (fid >= 10240) return;
  int j = fid >> 11, wi = fid & 2047;
  int gg = wi >> 7, rr = wi & 127;
  const float* src;
  uint4* dst;
  if (j < 3)      { src = W1 + rr * 384 + j * 128 + gg * 8; dst = W1f + j * 2048 + wi; }
  else if (j == 3){ src = W2 + rr * 128 + gg * 8;           dst = W2f + wi; }
  else            { src = W3 + rr * 128 + gg * 8;           dst = W3f + wi; }
  float4 a0 = *(const float4*)src, a1 = *(const float4*)(src + 4);
  uint4 u; u.x = pk2(a0.x, a0.y); u.y = pk2(a0.z, a0.w);
  u.z = pk2(a1.x, a1.y); u.w = pk2(a1.z, a1.w);
  *dst = u;
}

// per-batch sspecT (f32 [b][p][k]) -> frags sTf[b*2048 + gg*128 + p]
__global__ __launch_bounds__(256)
void k_wprep_spec(const float* __restrict__ sspecT, uint4* __restrict__ sTf)
{
  int fid = blockIdx.x * 256 + threadIdx.x;
  if (fid >= 8192) return;
  int b = fid >> 11, wi = fid & 2047;
  int gg = wi >> 7, p = wi & 127;
  const float* src = sspecT + ((size_t)b * P_ + p) * K_ + gg * 8;
  float4 a0 = *(const float4*)src, a1 = *(const float4*)(src + 4);
  uint4 u; u.x = pk2(a0.x, a0.y); u.y = pk2(a0.z, a0.w);
  u.z = pk2(a1.x, a1.y); u.w = pk2(a1.z, a1.w);
  sTf[(size_t)b * 2048 + wi] = u;
}

// ---------------------------------------------------------------------------
// spectral projection via MFMA: part[b][c][k][p] = sum_{n in chunk c} evT[k][n]*xT[p][n]
// ---------------------------------------------------------------------------
__device__ __forceinline__ void stg64(uint4* __restrict__ Ls,
                                      const __hip_bfloat16* __restrict__ G,
                                      int n0, int t)
{
#pragma unroll
  for (int i = 0; i < 2; ++i) {
    int gid = t + i * 512;
    int r = gid >> 3, kg = gid & 7;
    int n = n0 + kg * 8;
    uint4 u = make_uint4(0u, 0u, 0u, 0u);
    if (n < N_) u = *(const uint4*)(G + (size_t)r * N_ + n);  // N%8==0: full or none
    Ls[r * 8 + (kg ^ (r & 7))] = u;
  }
}

__global__ __launch_bounds__(512)
void k_spec_mm(const __hip_bfloat16* __restrict__ evT,
               const __hip_bfloat16* __restrict__ xT,
               float* __restrict__ part)
{
  const int c = blockIdx.x, b = blockIdx.y, t = threadIdx.x;
  const int l = t & 63, wid = t >> 6;
  const int wr = wid >> 2, wc = wid & 3;
  const int lr = l & 15, lg = l >> 4;
  __shared__ uint4 AsB[1024];
  __shared__ uint4 WsB[1024];
  f32x4 acc[4][2];
#pragma unroll
  for (int m = 0; m < 4; ++m)
#pragma unroll
    for (int n = 0; n < 2; ++n) acc[m][n] = (f32x4)0.f;

  const __hip_bfloat16* eb = evT + (size_t)b * 128 * N_;
  const __hip_bfloat16* xb = xT  + (size_t)b * 128 * N_;

  for (int s = 0; s < 4; ++s) {
    int n0 = c * 256 + s * 64;
    __syncthreads();
    stg64(AsB, eb, n0, t);
    stg64(WsB, xb, n0, t);
    __syncthreads();
    const short8* Ap = (const short8*)AsB;
    const short8* Wp = (const short8*)WsB;
#pragma unroll
    for (int kk = 0; kk < 2; ++kk) {
      int gg = kk * 4 + lg;
      short8 a[4], w[2];
#pragma unroll
      for (int m = 0; m < 4; ++m) { int rr = wr*64 + m*16 + lr; a[m] = Ap[rr*8 + (gg ^ (rr & 7))]; }
#pragma unroll
      for (int n = 0; n < 2; ++n) { int rr = wc*32 + n*16 + lr; w[n] = Wp[rr*8 + (gg ^ (rr & 7))]; }
#pragma unroll
      for (int m = 0; m < 4; ++m)
#pragma unroll
        for (int n = 0; n < 2; ++n)
          acc[m][n] = __builtin_amdgcn_mfma_f32_16x16x32_bf16(a[m], w[n], acc[m][n], 0, 0, 0);
    }
  }

  float* po = part + ((size_t)(b * NCH_S + c) << 14);
#pragma unroll
  for (int m = 0; m < 4; ++m)
#pragma unroll
    for (int r = 0; r < 4; ++r) {
      int row = wr*64 + m*16 + lg*4 + r;     // k index
#pragma unroll
      for (int n = 0; n < 2; ++n) {
        int col = wc*32 + n*16 + lr;         // p index
        po[row * 128 + col] = acc[m][n][r];
      }
    }
}

__global__ __launch_bounds__(256)
void k_spec_reduce(const float* __restrict__ partial, const float* __restrict__ evals,
                   const float* __restrict__ times, float* __restrict__ sspecT)
{
  int idx = blockIdx.x * 256 + threadIdx.x;
  int b = idx >> 14;
  int kp = idx & 16383;
  int k = kp >> 7, p = kp & 127;
  float s = 0.f;
  const float* pb = partial + (size_t)b * NCH_S * (K_*P_) + kp;
  for (int c = 0; c < NCH_S; ++c) s += pb[(size_t)c * (K_*P_)];
  float tt = times[p]; tt = tt < 1e-8f ? 1e-8f : tt;
  float sc = __expf(-evals[b*K_ + k] * tt);
  sspecT[((size_t)b*P_ + p) * K_ + k] = s * sc;
}

// ---------------------------------------------------------------------------
// 64-row-tile MFMA machinery (A in 16KB LDS, W-frags direct from global)
// ---------------------------------------------------------------------------
__device__ __forceinline__ void stg64r(uint4* __restrict__ Ls,
                                       const __hip_bfloat16* __restrict__ G,
                                       int nrows, int t)
{
#pragma unroll
  for (int i = 0; i < 4; ++i) {
    int gid = t + i * 256;              // 1024 frags: 64 rows x 16 kgroups
    int r = gid >> 4, kg = gid & 15;
    uint4 u = make_uint4(0u,0u,0u,0u);
    if (r < nrows) u = *(const uint4*)(G + (size_t)r * 128 + kg * 8);
    Ls[r * 16 + (kg ^ (r & 7))] = u;
  }
}

__device__ __forceinline__ void stg64r_f32(uint4* __restrict__ Ls,
                                           const float* __restrict__ G,
                                           int nrows, int t)
{
#pragma unroll
  for (int i = 0; i < 4; ++i) {
    int gid = t + i * 256;
    int r = gid >> 4, kg = gid & 15;
    float4 v0 = make_float4(0.f,0.f,0.f,0.f), v1 = v0;
    if (r < nrows) {
      const float* p = G + (size_t)r * 128 + kg * 8;
      v0 = *(const float4*)p;
      v1 = *(const float4*)(p + 4);
    }
    uint4 u;
    u.x = pk2(v0.x, v0.y); u.y = pk2(v0.z, v0.w);
    u.z = pk2(v1.x, v1.y); u.w = pk2(v1.z, v1.w);
    Ls[r * 16 + (kg ^ (r & 7))] = u;
  }
}

__device__ __forceinline__ void mfma_pass64(const uint4* As, const uint4* __restrict__ Wf,
                                            int wc, int lr, int lg, f32x4 acc[4][2])
{
  const short8* Ap = (const short8*)As;
  const short8* Wp = (const short8*)Wf;
#pragma unroll
  for (int kk = 0; kk < 4; ++kk) {
    int gg = kk * 4 + lg;
    short8 a[4], w[2];
#pragma unroll
    for (int m = 0; m < 4; ++m) { int rr = m*16 + lr; a[m] = Ap[rr*16 + (gg ^ (rr & 7))]; }
#pragma unroll
    for (int n = 0; n < 2; ++n) { int rr = wc*32 + n*16 + lr; w[n] = Wp[(gg << 7) + rr]; }
#pragma unroll
    for (int m = 0; m < 4; ++m)
#pragma unroll
      for (int n = 0; n < 2; ++n)
        acc[m][n] = __builtin_amdgcn_mfma_f32_16x16x32_bf16(a[m], w[n], acc[m][n], 0, 0, 0);
  }
}

// ---------------------------------------------------------------------------
// diffusion unproject: xd = evecs @ sspec  (64-row tiles, per-batch W-frags)
// ---------------------------------------------------------------------------
__global__ __launch_bounds__(256)
void k_unproj(const float* __restrict__ evecs, const uint4* __restrict__ sTf,
              __hip_bfloat16* __restrict__ xd)
{
  const int b = blockIdx.y, r0 = blockIdx.x * 64, t = threadIdx.x;
  const int l = t & 63, w = t >> 6;
  const int lr = l & 15, lg = l >> 4;
  __shared__ uint4 LA[1024];
  f32x4 acc[4][2];
#pragma unroll
  for (int m = 0; m < 4; ++m)
#pragma unroll
    for (int n = 0; n < 2; ++n) acc[m][n] = (f32x4)0.f;
  const int nrows = min(64, N_ - r0);
  stg64r_f32(LA, evecs + (size_t)b * N_ * 128 + (size_t)r0 * 128, nrows, t);
  __syncthreads();
  mfma_pass64(LA, sTf + (size_t)b * 2048, w, lr, lg, acc);
  __hip_bfloat16* xdb = xd + (size_t)b * N_ * P_;
#pragma unroll
  for (int m = 0; m < 4; ++m)
#pragma unroll
    for (int r = 0; r < 4; ++r) {
      int row = r0 + m*16 + lg*4 + r;
      if (row >= N_) continue;
#pragma unroll
      for (int n = 0; n < 2; ++n) {
        int col = w*32 + n*16 + lr;
        xdb[(size_t)row*128 + col] = __float2bfloat16(acc[m][n][r]);
      }
    }
}

// ---------------------------------------------------------------------------
// grad features v3 (unchanged)
// ---------------------------------------------------------------------------
__global__ __launch_bounds__(256)
void k_grad(const uint4* __restrict__ WfRe, const uint4* __restrict__ WfIm,
            __hip_bfloat16* __restrict__ gx, const __hip_bfloat16* __restrict__ gy)
{
  const int b = blockIdx.y, r0 = blockIdx.x * 64, t = threadIdx.x;
  const int l = t & 63, wc = t >> 6;
  const int lr = l & 15, lg = l >> 4;
  __shared__ uint4 As[1024];
  __shared__ uint4 As2[1024];
  f32x4 acc1[4][2], acc2[4][2];
#pragma unroll
  for (int m = 0; m < 4; ++m)
#pragma unroll
    for (int n = 0; n < 2; ++n) { acc1[m][n] = (f32x4)0.f; acc2[m][n] = (f32x4)0.f; }

  __hip_bfloat16*       gxb = gx + (size_t)b * N_ * P_;
  const __hip_bfloat16* gyb = gy + (size_t)b * N_ * P_;
  const int nrows = min(64, N_ - r0);

  stg64r(As,  gxb + (size_t)r0 * 128, nrows, t);
  stg64r(As2, gyb + (size_t)r0 * 128, nrows, t);
  __syncthreads();
  mfma_pass64(As,  WfRe, wc, lr, lg, acc1);
  mfma_pass64(As2, WfIm, wc, lr, lg, acc2);
  __syncthreads();

  short* S1 = (short*)As;
  short* S2 = (short*)As2;
#pragma unroll
  for (int m = 0; m < 4; ++m)
#pragma unroll
    for (int r = 0; r < 4; ++r) {
      int rowt = m*16 + lg*4 + r;
#pragma unroll
      for (int n = 0; n < 2; ++n) {
        int col = wc*32 + n*16 + lr;
        int idx = (rowt*16 + ((col>>3) ^ (rowt & 7)))*8 + (col & 7);
        S1[idx] = f2bs(acc1[m][n][r]);
        S2[idx] = f2bs(acc2[m][n][r]);
      }
    }
  __syncthreads();

  {
    const int row = t >> 2, cq = t & 3;
    if (row < nrows) {
      const short8* P1 = (const short8*)As;
      const short8* P2 = (const short8*)As2;
      const size_t gbase = (size_t)(r0 + row) * 128 + cq * 32;
#pragma unroll
      for (int cg = 0; cg < 4; ++cg) {
        int kg = cq * 4 + cg;
        short8 a1 = P1[row*16 + (kg ^ (row & 7))];
        short8 a2 = P2[row*16 + (kg ^ (row & 7))];
        uint4 ux = *(const uint4*)(gxb + gbase + cg*8);
        uint4 uy = *(const uint4*)(gyb + gbase + cg*8);
        unsigned xw[4] = {ux.x, ux.y, ux.z, ux.w};
        unsigned yw[4] = {uy.x, uy.y, uy.z, uy.w};
        unsigned ow[4];
#pragma unroll
        for (int p = 0; p < 4; ++p) {
          float g1l = __uint_as_float(xw[p] << 16);
          float g1h = __uint_as_float(xw[p] & 0xffff0000u);
          float g2l = __uint_as_float(yw[p] << 16);
          float g2h = __uint_as_float(yw[p] & 0xffff0000u);
          float sl = g1l * bf2f(a1[2*p])   + g2l * bf2f(a2[2*p]);
          float sh = g1h * bf2f(a1[2*p+1]) + g2h * bf2f(a2[2*p+1]);
          sl = fminf(fmaxf(sl, -15.f), 15.f);
          sh = fminf(fmaxf(sh, -15.f), 15.f);
          float el = __expf(2.f * sl), eh = __expf(2.f * sh);
          ow[p] = pk2((el - 1.f) / (el + 1.f), (eh - 1.f) / (eh + 1.f));
        }
        uint4 o; o.x = ow[0]; o.y = ow[1]; o.z = ow[2]; o.w = ow[3];
        *(uint4*)(gxb + gbase + cg*8) = o;
      }
    }
  }
}

// ---------------------------------------------------------------------------
// FUSED MLP v4: wave-independent, zero barriers, W-FRAGMENT REUSE x2.
// Each wave owns 32 rows (two 16-row A-sets); every W-fragment load feeds
// TWO MFMAs. h1/h2 via wave-private 8KB swizzled LDS. grid (ceil(N/128), B).
// ---------------------------------------------------------------------------
__global__ __launch_bounds__(256)
void k_mlp(const float* __restrict__ xin, const __hip_bfloat16* __restrict__ xd,
           const __hip_bfloat16* __restrict__ xg,
           const uint4* __restrict__ W1f, const uint4* __restrict__ W2f,
           const uint4* __restrict__ W3f,
           const float* __restrict__ b1, const float* __restrict__ b2,
           const float* __restrict__ b3, float* __restrict__ out)
{
  const int b = blockIdx.y, r0 = blockIdx.x * 128, t = threadIdx.x;
  const int l = t & 63, w = t >> 6;
  const int lr = l & 15, lg = l >> 4;
  __shared__ uint4 H[4][512];              // 8KB per wave: two 16x128 sub-tiles
  uint4* Hw = H[w];

  const int rbase = r0 + w * 32;           // wave's 32 output rows
  const int arow0 = min(rbase + lr,      N_ - 1);
  const int arow1 = min(rbase + 16 + lr, N_ - 1);
  const size_t boff = (size_t)b * N_ * 128;
  const float* xinb = xin + boff;

  f32x4 acc[2][8];
#pragma unroll
  for (int s = 0; s < 2; ++s)
#pragma unroll
    for (int n = 0; n < 8; ++n) acc[s][n] = (f32x4)0.f;

  // ---- layer 1, chunk 0: x_in (f32 -> bf16 frags on the fly) ----
#pragma unroll
  for (int kk = 0; kk < 4; ++kk) {
    union { uint4 u; short8 s; } af0, af1;
    {
      const float* p = xinb + (size_t)arow0 * 128 + kk * 32 + lg * 8;
      float4 v0 = *(const float4*)p, v1 = *(const float4*)(p + 4);
      af0.u.x = pk2(v0.x, v0.y); af0.u.y = pk2(v0.z, v0.w);
      af0.u.z = pk2(v1.x, v1.y); af0.u.w = pk2(v1.z, v1.w);
    }
    {
      const float* p = xinb + (size_t)arow1 * 128 + kk * 32 + lg * 8;
      float4 v0 = *(const float4*)p, v1 = *(const float4*)(p + 4);
      af1.u.x = pk2(v0.x, v0.y); af1.u.y = pk2(v0.z, v0.w);
      af1.u.z = pk2(v1.x, v1.y); af1.u.w = pk2(v1.z, v1.w);
    }
    const int kg = (kk << 2) + lg;
#pragma unroll
    for (int n = 0; n < 8; ++n) {
      union { uint4 u; short8 s; } wf; wf.u = W1f[(kg << 7) + n*16 + lr];
      acc[0][n] = __builtin_amdgcn_mfma_f32_16x16x32_bf16(af0.s, wf.s, acc[0][n], 0, 0, 0);
      acc[1][n] = __builtin_amdgcn_mfma_f32_16x16x32_bf16(af1.s, wf.s, acc[1][n], 0, 0, 0);
    }
  }
  // ---- layer 1, chunks 1 (xd) and 2 (xg), bf16 direct ----
#pragma unroll
  for (int c = 1; c < 3; ++c) {
    const __hip_bfloat16* src = (c == 1 ? xd : xg) + boff;
#pragma unroll
    for (int kk = 0; kk < 4; ++kk) {
      union { uint4 u; short8 s; } af0, af1;
      af0.u = *(const uint4*)(src + (size_t)arow0 * 128 + kk * 32 + lg * 8);
      af1.u = *(const uint4*)(src + (size_t)arow1 * 128 + kk * 32 + lg * 8);
      const int kg = (kk << 2) + lg;
#pragma unroll
      for (int n = 0; n < 8; ++n) {
        union { uint4 u; short8 s; } wf; wf.u = W1f[(c << 11) + (kg << 7) + n*16 + lr];
        acc[0][n] = __builtin_amdgcn_mfma_f32_16x16x32_bf16(af0.s, wf.s, acc[0][n], 0, 0, 0);
        acc[1][n] = __builtin_amdgcn_mfma_f32_16x16x32_bf16(af1.s, wf.s, acc[1][n], 0, 0, 0);
      }
    }
  }

  // h1 = relu(acc+b1) -> wave-private LDS (swizzled A-frag layout), no barrier
#pragma unroll
  for (int s = 0; s < 2; ++s) {
    short* Hs = (short*)(Hw + s * 256);
#pragma unroll
    for (int n = 0; n < 8; ++n) {
      float bb = b1[n*16 + lr];
#pragma unroll
      for (int r = 0; r < 4; ++r) {
        int rowt = lg*4 + r;
        int col = n*16 + lr;
        float v = fmaxf(acc[s][n][r] + bb, 0.f);
        Hs[(rowt*16 + ((col>>3) ^ (rowt & 7)))*8 + (col & 7)] = f2bs(v);
      }
    }
  }

  // ---- layer 2: A-frags from Hw (wave-local) ----
#pragma unroll
  for (int s = 0; s < 2; ++s)
#pragma unroll
    for (int n = 0; n < 8; ++n) acc[s][n] = (f32x4)0.f;
#pragma unroll
  for (int kk = 0; kk < 4; ++kk) {
    const int kg = (kk << 2) + lg;
    short8 a0 = ((const short8*)(Hw))[lr*16 + (kg ^ (lr & 7))];
    short8 a1 = ((const short8*)(Hw + 256))[lr*16 + (kg ^ (lr & 7))];
#pragma unroll
    for (int n = 0; n < 8; ++n) {
      union { uint4 u; short8 s; } wf; wf.u = W2f[(kg << 7) + n*16 + lr];
      acc[0][n] = __builtin_amdgcn_mfma_f32_16x16x32_bf16(a0, wf.s, acc[0][n], 0, 0, 0);
      acc[1][n] = __builtin_amdgcn_mfma_f32_16x16x32_bf16(a1, wf.s, acc[1][n], 0, 0, 0);
    }
  }
  // h2 = relu(acc+b2) -> Hw (reuse; wave program order guarantees h1 reads done)
#pragma unroll
  for (int s = 0; s < 2; ++s) {
    short* Hs = (short*)(Hw + s * 256);
#pragma unroll
    for (int n = 0; n < 8; ++n) {
      float bb = b2[n*16 + lr];
#pragma unroll
      for (int r = 0; r < 4; ++r) {
        int rowt = lg*4 + r;
        int col = n*16 + lr;
        float v = fmaxf(acc[s][n][r] + bb, 0.f);
        Hs[(rowt*16 + ((col>>3) ^ (rowt & 7)))*8 + (col & 7)] = f2bs(v);
      }
    }
  }

  // ---- layer 3 + direct epilogue (bias + residual) ----
#pragma unroll
  for (int s = 0; s < 2; ++s)
#pragma unroll
    for (int n = 0; n < 8; ++n) acc[s][n] = (f32x4)0.f;
#pragma unroll
  for (int kk = 0; kk < 4; ++kk) {
    const int kg = (kk << 2) + lg;
    short8 a0 = ((const short8*)(Hw))[lr*16 + (kg ^ (lr & 7))];
    short8 a1 = ((const short8*)(Hw + 256))[lr*16 + (kg ^ (lr & 7))];
#pragma unroll
    for (int n = 0; n < 8; ++n) {
      union { uint4 u; short8 s; } wf; wf.u = W3f[(kg << 7) + n*16 + lr];
      acc[0][n] = __builtin_amdgcn_mfma_f32_16x16x32_bf16(a0, wf.s, acc[0][n], 0, 0, 0);
      acc[1][n] = __builtin_amdgcn_mfma_f32_16x16x32_bf16(a1, wf.s, acc[1][n], 0, 0, 0);
    }
  }
  {
    float* ob = out + boff;
#pragma unroll
    for (int s = 0; s < 2; ++s)
#pragma unroll
      for (int n = 0; n < 8; ++n) {
        float bb = b3[n*16 + lr];
#pragma unroll
        for (int r = 0; r < 4; ++r) {
          int row = rbase + s*16 + lg*4 + r;
          if (row >= N_) continue;
          int col = n*16 + lr;
          float v = acc[s][n][r] + bb + xinb[(size_t)row*128 + col];
          ob[(size_t)row*128 + col] = v;
        }
      }
  }
}

// ---------------------------------------------------------------------------
// SpMM: count -> hierarchical scan (blk/top/add) -> fill (packed recs) -> gather
// ---------------------------------------------------------------------------
__global__ void k_count(const int* __restrict__ rows, int* __restrict__ cnt)
{
  int b = blockIdx.y;
  int e = blockIdx.x * 256 + threadIdx.x;
  if (e < E_) atomicAdd(&cnt[b*N_ + rows[(size_t)b*E_ + e]], 1);
}

__global__ __launch_bounds__(256)
void k_scan_blk(const int* __restrict__ cnt, int* __restrict__ off,
                int* __restrict__ bsum)
{
  const int c = blockIdx.x, b = blockIdx.y, t = threadIdx.x;
  const int lane = t & 63, wid = t >> 6;
  __shared__ int wt[4];
  int i = c * 256 + t;
  int v = (i < N_) ? cnt[b*N_ + i] : 0;
  int x = v;
#pragma unroll
  for (int ofs = 1; ofs < 64; ofs <<= 1) {
    int y = __shfl_up(x, ofs, 64);
    if (lane >= ofs) x += y;
  }
  if (lane == 63) wt[wid] = x;
  __syncthreads();
  int wofs = 0;
  for (int wj = 0; wj < wid; ++wj) wofs += wt[wj];
  if (i < N_) off[b*(N_+1) + i] = wofs + x - v;
  if (t == 255) bsum[b*128 + c] = wofs + x;
}

__global__ __launch_bounds__(64)
void k_scan_top(int* __restrict__ bsum, int* __restrict__ off)
{
  const int b = blockIdx.x, t = threadIdx.x;
  int running = 0;
  for (int base = 0; base < 128; base += 64) {
    int i = base + t;
    int v = (i < NSCB) ? bsum[b*128 + i] : 0;
    int x = v;
#pragma unroll
    for (int ofs = 1; ofs < 64; ofs <<= 1) {
      int y = __shfl_up(x, ofs, 64);
      if (t >= ofs) x += y;
    }
    if (i < 128) bsum[b*128 + i] = running + x - v;
    running += __shfl(x, 63, 64);
  }
  if (t == 0) off[b*(N_+1) + N_] = running;
}

__global__ __launch_bounds__(256)
void k_scan_add(const int* __restrict__ bsum, int* __restrict__ off,
                int* __restrict__ pos)
{
  const int c = blockIdx.x, b = blockIdx.y;
  int i = c * 256 + (int)threadIdx.x;
  if (i < N_) {
    int o = off[b*(N_+1) + i] + bsum[b*128 + c];
    off[b*(N_+1) + i] = o;
    pos[b*N_ + i] = o;
  }
}

__global__ void k_fill(const int* __restrict__ rows, const int* __restrict__ cols,
                       const float* __restrict__ vx, const float* __restrict__ vy,
                       int* __restrict__ pos, uint4* __restrict__ prec)
{
  int b = blockIdx.y;
  int e = blockIdx.x * 256 + threadIdx.x;
  if (e < E_) {
    size_t be = (size_t)b*E_ + e;
    int r = rows[be];
    int p = atomicAdd(&pos[b*N_ + r], 1);
    if (p >= 0 && p < E_) {
      uint4 rec;
      rec.x = (unsigned)cols[be];
      rec.y = __float_as_uint(vx[be]);
      rec.z = __float_as_uint(vy[be]);
      rec.w = 0u;
      prec[(size_t)b*E_ + p] = rec;
    }
  }
}

// wave per row; quarter-wave per edge, unrolled 2x (8 edges in flight)
__global__ __launch_bounds__(256)
void k_gather(const __hip_bfloat16* __restrict__ xd, const uint4* __restrict__ prec,
              const int* __restrict__ off,
              __hip_bfloat16* __restrict__ gx, __hip_bfloat16* __restrict__ gy)
{
  const int b = blockIdx.y;
  const int row = (blockIdx.x * 256 + threadIdx.x) >> 6;
  const int lane = threadIdx.x & 63;
  const int q = lane >> 4, ql = lane & 15;
  if (row >= N_) return;
  const int s = off[b*(N_+1) + row], e = off[b*(N_+1) + row + 1];
  float ax[8], ay[8];
#pragma unroll
  for (int k = 0; k < 8; ++k) { ax[k] = 0.f; ay[k] = 0.f; }
  const __hip_bfloat16* xdb = xd + (size_t)b * N_ * P_;
  const uint4* pb = prec + (size_t)b * E_;

  for (int i = s; i < e; i += 8) {
    int idx0 = i + q, idx1 = i + 4 + q;
    bool v0 = idx0 < e, v1 = idx1 < e;
    uint4 rec0 = pb[v0 ? idx0 : (e - 1)];
    uint4 rec1 = pb[v1 ? idx1 : (e - 1)];
    float fx0 = v0 ? __uint_as_float(rec0.y) : 0.f;
    float fy0 = v0 ? __uint_as_float(rec0.z) : 0.f;
    float fx1 = v1 ? __uint_as_float(rec1.y) : 0.f;
    float fy1 = v1 ? __uint_as_float(rec1.z) : 0.f;
    uint4 va = *(const uint4*)(xdb + (size_t)rec0.x * P_ + ql * 8);
    uint4 vb = *(const uint4*)(xdb + (size_t)rec1.x * P_ + ql * 8);
    unsigned aw[4] = {va.x, va.y, va.z, va.w};
    unsigned bw[4] = {vb.x, vb.y, vb.z, vb.w};
#pragma unroll
    for (int p = 0; p < 4; ++p) {
      float a_lo = __uint_as_float(aw[p] << 16);
      float a_hi = __uint_as_float(aw[p] & 0xffff0000u);
      float b_lo = __uint_as_float(bw[p] << 16);
      float b_hi = __uint_as_float(bw[p] & 0xffff0000u);
      ax[2*p]   = fmaf(fx0, a_lo, ax[2*p]);   ax[2*p]   = fmaf(fx1, b_lo, ax[2*p]);
      ax[2*p+1] = fmaf(fx0, a_hi, ax[2*p+1]); ax[2*p+1] = fmaf(fx1, b_hi, ax[2*p+1]);
      ay[2*p]   = fmaf(fy0, a_lo, ay[2*p]);   ay[2*p]   = fmaf(fy1, b_lo, ay[2*p]);
      ay[2*p+1] = fmaf(fy0, a_hi, ay[2*p+1]); ay[2*p+1] = fmaf(fy1, b_hi, ay[2*p+1]);
    }
  }
#pragma unroll
  for (int k = 0; k < 8; ++k) {
    ax[k] += __shfl_xor(ax[k], 16, 64); ax[k] += __shfl_xor(ax[k], 32, 64);
    ay[k] += __shfl_xor(ay[k], 16, 64); ay[k] += __shfl_xor(ay[k], 32, 64);
  }
  if (lane < 16) {
    size_t o = (size_t)b * N_ * P_ + (size_t)row * P_ + ql * 8;
    uint4 ux, uy;
    ux.x = pk2(ax[0], ax[1]); ux.y = pk2(ax[2], ax[3]);
    ux.z = pk2(ax[4], ax[5]); ux.w = pk2(ax[6], ax[7]);
    uy.x = pk2(ay[0], ay[1]); uy.y = pk2(ay[2], ay[3]);
    uy.z = pk2(ay[4], ay[5]); uy.w = pk2(ay[6], ay[7]);
    *(uint4*)(gx + o) = ux;
    *(uint4*)(gy + o) = uy;
  }
}

// ---------------------------------------------------------------------------
extern "C" void kernel_launch(void* const* d_in, const int* in_sizes, int n_in,
                              void* d_out, int out_size, void* d_ws, size_t ws_size,
                              hipStream_t stream)
{
  const float* x_in  = (const float*)d_in[0];
  const float* areas = (const float*)d_in[1];
  const float* evals = (const float*)d_in[2];
  const float* evecs = (const float*)d_in[3];
  const float* gXv   = (const float*)d_in[4];
  const float* gYv   = (const float*)d_in[5];
  const int*   grows = (const int*)d_in[6];
  const int*   gcols = (const int*)d_in[7];
  const float* times = (const float*)d_in[8];
  const float* Bre   = (const float*)d_in[9];
  const float* Bim   = (const float*)d_in[10];
  const float* W1    = (const float*)d_in[11];
  const float* b1    = (const float*)d_in[12];
  const float* W2    = (const float*)d_in[13];
  const float* b2    = (const float*)d_in[14];
  const float* W3    = (const float*)d_in[15];
  const float* b3    = (const float*)d_in[16];

  float* ws = (float*)d_ws;
  // ws layout (float offsets) — d_out WRITE-ONLY:
  //   xd_bf [0, 5.12M) | part [6M, 11.18M) | gx/xg [12M, 17.12M) | gy [18M, 23.12M)
  //   scratch [24M, ~26.91M): prec | ipos | ioff | sspecT | WfRe | WfIm | bsum |
  //                           W1f | W2f | W3f | sTf
  __hip_bfloat16* xd_bf = (__hip_bfloat16*)ws;                  // x_diffuse bf16
  float*          part  = ws + 6000000;                         // fp32 partials
  __hip_bfloat16* gx_bf = (__hip_bfloat16*)(ws + 12000000);     // evT -> gx -> xg
  __hip_bfloat16* gy_bf = (__hip_bfloat16*)(ws + 18000000);     // xT  -> gy
  __hip_bfloat16* evT   = gx_bf;
  __hip_bfloat16* xT    = gy_bf;

  uint4* prec   = (uint4*)(ws + 24000000);          // B*E packed records
  int*   ipos   = (int*)(ws + 26560000);            // B*N counts/cursor
  int*   ioff   = ipos + B_*N_;                     // B*(N+1) offsets
  float* sspecT = ws + 26750000;                    // B*P*K fp32
  uint4* WfRe   = (uint4*)(ws + 26816000);          // 2048 uint4
  uint4* WfIm   = WfRe + 2048;                      // 2048 uint4
  int*   bsum   = (int*)(WfIm + 2048);              // B*128 block sums
  uint4* W1f    = (uint4*)(ws + 26834000);          // 3*2048 uint4
  uint4* W2f    = W1f + 6144;                       // 2048
  uint4* W3f    = W2f + 2048;                       // 2048
  uint4* sTf    = W3f + 2048;                       // B*2048
  float* out    = (float*)d_out;

  const int TN  = (N_ + 63) / 64;    // 313 64-row tiles
  const int TN2 = (N_ + 127) / 128;  // 157 128-row tiles (k_mlp v4)

  // spectral projection: transpose-prep -> MFMA split-K -> reduce+scale
  k_prep<<<dim3(TN, 4, B_), 256, 0, stream>>>(evecs, x_in, areas, evT, xT);
  k_wprep<<<dim3(8), 256, 0, stream>>>(Bre, Bim, WfRe, WfIm);
  k_wprep_mlp<<<dim3(40), 256, 0, stream>>>(W1, W2, W3, W1f, W2f, W3f);
  k_spec_mm<<<dim3(NCH_S, B_), 512, 0, stream>>>(evT, xT, part);
  k_spec_reduce<<<dim3(B_*K_*P_/256), 256, 0, stream>>>(part, evals, times, sspecT);
  k_wprep_spec<<<dim3(32), 256, 0, stream>>>(sspecT, sTf);
  // x_diffuse = evecs @ sspec (64-row tiles, per-batch W-frags) -> bf16
  k_unproj<<<dim3(TN, B_), 256, 0, stream>>>(evecs, sTf, xd_bf);
  // sparse gradient via counting sort (hierarchical scan, packed records)
  hipMemsetAsync(ipos, 0, (size_t)B_*N_*sizeof(int), stream);
  k_count<<<dim3(E_/256, B_), 256, 0, stream>>>(grows, ipos);
  k_scan_blk<<<dim3(NSCB, B_), 256, 0, stream>>>(ipos, ioff, bsum);
  k_scan_top<<<dim3(B_), 64, 0, stream>>>(bsum, ioff);
  k_scan_add<<<dim3(NSCB, B_), 256, 0, stream>>>(bsum, ioff, ipos);
  k_fill<<<dim3(E_/256, B_), 256, 0, stream>>>(grows, gcols, gXv, gYv, ipos, prec);
  k_gather<<<dim3(N_/4, B_), 256, 0, stream>>>(xd_bf, prec, ioff, gx_bf, gy_bf);
  // grad features (in place over gx -> xg)
  k_grad<<<dim3(TN, B_), 256, 0, stream>>>(WfRe, WfIm, gx_bf, gy_bf);
  // fused 3-layer MLP + residual -> d_out (wave-independent, W-reuse x2)
  k_mlp<<<dim3(TN2, B_), 256, 0, stream>>>(x_in, xd_bf, gx_bf, W1f, W2f, W3f,
                                           b1, b2, b3, out);
}

// Round 19
// 238.479 us; speedup vs baseline: 1.1476x; 1.1476x over previous
//
#include <hip/hip_runtime.h>
#include <hip/hip_bf16.h>
#include <cstddef>

#define B_ 4
#define N_ 20000
#define P_ 128
#define K_ 128
#define E_ 160000

constexpr int NCH_S = 79;   // ceil(N/256) split-K chunks for spectral projection
constexpr int NSCB  = 79;   // ceil(N/256) scan blocks

typedef __attribute__((ext_vector_type(8))) short short8;
typedef __attribute__((ext_vector_type(4))) float f32x4;

__device__ __forceinline__ unsigned pk2(float x, float y) {
  __hip_bfloat162 h = __float22bfloat162_rn(make_float2(x, y));  // RNE pack
  union { __hip_bfloat162 h; unsigned u; } c; c.h = h; return c.u;
}
__device__ __forceinline__ float bf2f(short s) {
  union { unsigned u; float f; } c; c.u = ((unsigned)(unsigned short)s) << 16; return c.f;
}
__device__ __forceinline__ short f2bs(float x) {
  union { __hip_bfloat16 h; short s; } c; c.h = __float2bfloat16(x); return c.s;
}

// ---------------------------------------------------------------------------
// prep: transpose+scale+bf16.  evT[b][k][n] = bf16(ev[b][n][k]*area[b][n]),
//       xT[b][p][n] = bf16(x[b][n][p]).   grid (ceil(N/64), 2half*2mat, B)
// ---------------------------------------------------------------------------
__global__ __launch_bounds__(256)
void k_prep(const float* __restrict__ ev, const float* __restrict__ xin,
            const float* __restrict__ areas,
            __hip_bfloat16* __restrict__ evT, __hip_bfloat16* __restrict__ xT)
{
  const int tn = blockIdx.x, half = blockIdx.y & 1, mat = blockIdx.y >> 1;
  const int b = blockIdx.z, t = threadIdx.x;
  const int n0 = tn * 64, c0 = half * 64;
  __shared__ float ld[64][65];
  const float* src = (mat ? xin : ev) + (size_t)b * N_ * 128;
  const float* ab  = areas + (size_t)b * N_;
#pragma unroll
  for (int i = 0; i < 4; ++i) {
    int gid = t + i * 256;
    int r = gid >> 4, c4 = (gid & 15) << 2;
    int n = n0 + r;
    float4 v = make_float4(0.f, 0.f, 0.f, 0.f);
    if (n < N_) {
      v = *(const float4*)(src + (size_t)n * 128 + c0 + c4);
      if (mat == 0) { float ar = ab[n]; v.x *= ar; v.y *= ar; v.z *= ar; v.w *= ar; }
    }
    ld[r][c4] = v.x; ld[r][c4+1] = v.y; ld[r][c4+2] = v.z; ld[r][c4+3] = v.w;
  }
  __syncthreads();
  __hip_bfloat16* dst = (mat ? xT : evT) + (size_t)b * 128 * N_;
#pragma unroll
  for (int i = 0; i < 4; ++i) {
    int gid = t + i * 256;
    int cr = gid >> 4, nq = (gid & 15) << 2;
    int n = n0 + nq;
    if (n + 4 <= N_) {                      // N%4==0: never a partial quad
      uint2 u;
      u.x = pk2(ld[nq][cr],   ld[nq+1][cr]);
      u.y = pk2(ld[nq+2][cr], ld[nq+3][cr]);
      *(uint2*)(dst + (size_t)(c0 + cr) * N_ + n) = u;
    }
  }
}

// ---------------------------------------------------------------------------
// W-fragment preps: frag[gg*128+rr] = bf16x8 of W[rr][koff+gg*8 .. +7]
// ---------------------------------------------------------------------------
__global__ __launch_bounds__(256)
void k_wprep(const float* __restrict__ Bre, const float* __restrict__ Bim,
             uint4* __restrict__ WfRe, uint4* __restrict__ WfIm)
{
  int fid = blockIdx.x * 256 + threadIdx.x;
  if (fid >= 2048) return;
  int gg = fid >> 7, rr = fid & 127;
  const float* s0 = Bre + rr * 128 + gg * 8;
  const float* s1 = Bim + rr * 128 + gg * 8;
  float4 a0 = *(const float4*)s0, a1 = *(const float4*)(s0 + 4);
  uint4 u; u.x = pk2(a0.x, a0.y); u.y = pk2(a0.z, a0.w);
  u.z = pk2(a1.x, a1.y); u.w = pk2(a1.z, a1.w);
  WfRe[fid] = u;
  float4 b0 = *(const float4*)s1, b1 = *(const float4*)(s1 + 4);
  uint4 v; v.x = pk2(b0.x, b0.y); v.y = pk2(b0.z, b0.w);
  v.z = pk2(b1.x, b1.y); v.w = pk2(b1.z, b1.w);
  WfIm[fid] = v;
}

// W1 (3 chunks of 128 cols, ldw=384), W2, W3 (ldw=128) -> 5 jobs x 2048 frags
__global__ __launch_bounds__(256)
void k_wprep_mlp(const float* __restrict__ W1, const float* __restrict__ W2,
                 const float* __restrict__ W3, uint4* __restrict__ W1f,
                 uint4* __restrict__ W2f, uint4* __restrict__ W3f)
{
  int fid = blockIdx.x * 256 + threadIdx.x;
  if (fid >= 10240) return;
  int j = fid >> 11, wi = fid & 2047;
  int gg = wi >> 7, rr = wi & 127;
  const float* src;
  uint4* dst;
  if (j < 3)      { src = W1 + rr * 384 + j * 128 + gg * 8; dst = W1f + j * 2048 + wi; }
  else if (j == 3){ src = W2 + rr * 128 + gg * 8;           dst = W2f + wi; }
  else            { src = W3 + rr * 128 + gg * 8;           dst = W3f + wi; }
  float4 a0 = *(const float4*)src, a1 = *(const float4*)(src + 4);
  uint4 u; u.x = pk2(a0.x, a0.y); u.y = pk2(a0.z, a0.w);
  u.z = pk2(a1.x, a1.y); u.w = pk2(a1.z, a1.w);
  *dst = u;
}

// per-batch sspecT (f32 [b][p][k]) -> frags sTf[b*2048 + gg*128 + p]
__global__ __launch_bounds__(256)
void k_wprep_spec(const float* __restrict__ sspecT, uint4* __restrict__ sTf)
{
  int fid = blockIdx.x * 256 + threadIdx.x;
  if (fid >= 8192) return;
  int b = fid >> 11, wi = fid & 2047;
  int gg = wi >> 7, p = wi & 127;
  const float* src = sspecT + ((size_t)b * P_ + p) * K_ + gg * 8;
  float4 a0 = *(const float4*)src, a1 = *(const float4*)(src + 4);
  uint4 u; u.x = pk2(a0.x, a0.y); u.y = pk2(a0.z, a0.w);
  u.z = pk2(a1.x, a1.y); u.w = pk2(a1.z, a1.w);
  sTf[(size_t)b * 2048 + wi] = u;
}

// ---------------------------------------------------------------------------
// spectral projection via MFMA: part[b][c][k][p] = sum_{n in chunk c} evT[k][n]*xT[p][n]
// ---------------------------------------------------------------------------
__device__ __forceinline__ void stg64(uint4* __restrict__ Ls,
                                      const __hip_bfloat16* __restrict__ G,
                                      int n0, int t)
{
#pragma unroll
  for (int i = 0; i < 2; ++i) {
    int gid = t + i * 512;
    int r = gid >> 3, kg = gid & 7;
    int n = n0 + kg * 8;
    uint4 u = make_uint4(0u, 0u, 0u, 0u);
    if (n < N_) u = *(const uint4*)(G + (size_t)r * N_ + n);  // N%8==0: full or none
    Ls[r * 8 + (kg ^ (r & 7))] = u;
  }
}

__global__ __launch_bounds__(512)
void k_spec_mm(const __hip_bfloat16* __restrict__ evT,
               const __hip_bfloat16* __restrict__ xT,
               float* __restrict__ part)
{
  const int c = blockIdx.x, b = blockIdx.y, t = threadIdx.x;
  const int l = t & 63, wid = t >> 6;
  const int wr = wid >> 2, wc = wid & 3;
  const int lr = l & 15, lg = l >> 4;
  __shared__ uint4 AsB[1024];
  __shared__ uint4 WsB[1024];
  f32x4 acc[4][2];
#pragma unroll
  for (int m = 0; m < 4; ++m)
#pragma unroll
    for (int n = 0; n < 2; ++n) acc[m][n] = (f32x4)0.f;

  const __hip_bfloat16* eb = evT + (size_t)b * 128 * N_;
  const __hip_bfloat16* xb = xT  + (size_t)b * 128 * N_;

  for (int s = 0; s < 4; ++s) {
    int n0 = c * 256 + s * 64;
    __syncthreads();
    stg64(AsB, eb, n0, t);
    stg64(WsB, xb, n0, t);
    __syncthreads();
    const short8* Ap = (const short8*)AsB;
    const short8* Wp = (const short8*)WsB;
#pragma unroll
    for (int kk = 0; kk < 2; ++kk) {
      int gg = kk * 4 + lg;
      short8 a[4], w[2];
#pragma unroll
      for (int m = 0; m < 4; ++m) { int rr = wr*64 + m*16 + lr; a[m] = Ap[rr*8 + (gg ^ (rr & 7))]; }
#pragma unroll
      for (int n = 0; n < 2; ++n) { int rr = wc*32 + n*16 + lr; w[n] = Wp[rr*8 + (gg ^ (rr & 7))]; }
#pragma unroll
      for (int m = 0; m < 4; ++m)
#pragma unroll
        for (int n = 0; n < 2; ++n)
          acc[m][n] = __builtin_amdgcn_mfma_f32_16x16x32_bf16(a[m], w[n], acc[m][n], 0, 0, 0);
    }
  }

  float* po = part + ((size_t)(b * NCH_S + c) << 14);
#pragma unroll
  for (int m = 0; m < 4; ++m)
#pragma unroll
    for (int r = 0; r < 4; ++r) {
      int row = wr*64 + m*16 + lg*4 + r;     // k index
#pragma unroll
      for (int n = 0; n < 2; ++n) {
        int col = wc*32 + n*16 + lr;         // p index
        po[row * 128 + col] = acc[m][n][r];
      }
    }
}

__global__ __launch_bounds__(256)
void k_spec_reduce(const float* __restrict__ partial, const float* __restrict__ evals,
                   const float* __restrict__ times, float* __restrict__ sspecT)
{
  int idx = blockIdx.x * 256 + threadIdx.x;
  int b = idx >> 14;
  int kp = idx & 16383;
  int k = kp >> 7, p = kp & 127;
  float s = 0.f;
  const float* pb = partial + (size_t)b * NCH_S * (K_*P_) + kp;
  for (int c = 0; c < NCH_S; ++c) s += pb[(size_t)c * (K_*P_)];
  float tt = times[p]; tt = tt < 1e-8f ? 1e-8f : tt;
  float sc = __expf(-evals[b*K_ + k] * tt);
  sspecT[((size_t)b*P_ + p) * K_ + k] = s * sc;
}

// ---------------------------------------------------------------------------
// 64-row-tile MFMA machinery (A in 16KB LDS, W-frags direct from global)
// ---------------------------------------------------------------------------
__device__ __forceinline__ void stg64r(uint4* __restrict__ Ls,
                                       const __hip_bfloat16* __restrict__ G,
                                       int nrows, int t)
{
#pragma unroll
  for (int i = 0; i < 4; ++i) {
    int gid = t + i * 256;              // 1024 frags: 64 rows x 16 kgroups
    int r = gid >> 4, kg = gid & 15;
    uint4 u = make_uint4(0u,0u,0u,0u);
    if (r < nrows) u = *(const uint4*)(G + (size_t)r * 128 + kg * 8);
    Ls[r * 16 + (kg ^ (r & 7))] = u;
  }
}

__device__ __forceinline__ void stg64r_f32(uint4* __restrict__ Ls,
                                           const float* __restrict__ G,
                                           int nrows, int t)
{
#pragma unroll
  for (int i = 0; i < 4; ++i) {
    int gid = t + i * 256;
    int r = gid >> 4, kg = gid & 15;
    float4 v0 = make_float4(0.f,0.f,0.f,0.f), v1 = v0;
    if (r < nrows) {
      const float* p = G + (size_t)r * 128 + kg * 8;
      v0 = *(const float4*)p;
      v1 = *(const float4*)(p + 4);
    }
    uint4 u;
    u.x = pk2(v0.x, v0.y); u.y = pk2(v0.z, v0.w);
    u.z = pk2(v1.x, v1.y); u.w = pk2(v1.z, v1.w);
    Ls[r * 16 + (kg ^ (r & 7))] = u;
  }
}

__device__ __forceinline__ void mfma_pass64(const uint4* As, const uint4* __restrict__ Wf,
                                            int wc, int lr, int lg, f32x4 acc[4][2])
{
  const short8* Ap = (const short8*)As;
  const short8* Wp = (const short8*)Wf;
#pragma unroll
  for (int kk = 0; kk < 4; ++kk) {
    int gg = kk * 4 + lg;
    short8 a[4], w[2];
#pragma unroll
    for (int m = 0; m < 4; ++m) { int rr = m*16 + lr; a[m] = Ap[rr*16 + (gg ^ (rr & 7))]; }
#pragma unroll
    for (int n = 0; n < 2; ++n) { int rr = wc*32 + n*16 + lr; w[n] = Wp[(gg << 7) + rr]; }
#pragma unroll
    for (int m = 0; m < 4; ++m)
#pragma unroll
      for (int n = 0; n < 2; ++n)
        acc[m][n] = __builtin_amdgcn_mfma_f32_16x16x32_bf16(a[m], w[n], acc[m][n], 0, 0, 0);
  }
}

// ---------------------------------------------------------------------------
// diffusion unproject: xd = evecs @ sspec  (64-row tiles, per-batch W-frags)
// ---------------------------------------------------------------------------
__global__ __launch_bounds__(256)
void k_unproj(const float* __restrict__ evecs, const uint4* __restrict__ sTf,
              __hip_bfloat16* __restrict__ xd)
{
  const int b = blockIdx.y, r0 = blockIdx.x * 64, t = threadIdx.x;
  const int l = t & 63, w = t >> 6;
  const int lr = l & 15, lg = l >> 4;
  __shared__ uint4 LA[1024];
  f32x4 acc[4][2];
#pragma unroll
  for (int m = 0; m < 4; ++m)
#pragma unroll
    for (int n = 0; n < 2; ++n) acc[m][n] = (f32x4)0.f;
  const int nrows = min(64, N_ - r0);
  stg64r_f32(LA, evecs + (size_t)b * N_ * 128 + (size_t)r0 * 128, nrows, t);
  __syncthreads();
  mfma_pass64(LA, sTf + (size_t)b * 2048, w, lr, lg, acc);
  __hip_bfloat16* xdb = xd + (size_t)b * N_ * P_;
#pragma unroll
  for (int m = 0; m < 4; ++m)
#pragma unroll
    for (int r = 0; r < 4; ++r) {
      int row = r0 + m*16 + lg*4 + r;
      if (row >= N_) continue;
#pragma unroll
      for (int n = 0; n < 2; ++n) {
        int col = w*32 + n*16 + lr;
        xdb[(size_t)row*128 + col] = __float2bfloat16(acc[m][n][r]);
      }
    }
}

// ---------------------------------------------------------------------------
// grad features v3 (unchanged)
// ---------------------------------------------------------------------------
__global__ __launch_bounds__(256)
void k_grad(const uint4* __restrict__ WfRe, const uint4* __restrict__ WfIm,
            __hip_bfloat16* __restrict__ gx, const __hip_bfloat16* __restrict__ gy)
{
  const int b = blockIdx.y, r0 = blockIdx.x * 64, t = threadIdx.x;
  const int l = t & 63, wc = t >> 6;
  const int lr = l & 15, lg = l >> 4;
  __shared__ uint4 As[1024];
  __shared__ uint4 As2[1024];
  f32x4 acc1[4][2], acc2[4][2];
#pragma unroll
  for (int m = 0; m < 4; ++m)
#pragma unroll
    for (int n = 0; n < 2; ++n) { acc1[m][n] = (f32x4)0.f; acc2[m][n] = (f32x4)0.f; }

  __hip_bfloat16*       gxb = gx + (size_t)b * N_ * P_;
  const __hip_bfloat16* gyb = gy + (size_t)b * N_ * P_;
  const int nrows = min(64, N_ - r0);

  stg64r(As,  gxb + (size_t)r0 * 128, nrows, t);
  stg64r(As2, gyb + (size_t)r0 * 128, nrows, t);
  __syncthreads();
  mfma_pass64(As,  WfRe, wc, lr, lg, acc1);
  mfma_pass64(As2, WfIm, wc, lr, lg, acc2);
  __syncthreads();

  short* S1 = (short*)As;
  short* S2 = (short*)As2;
#pragma unroll
  for (int m = 0; m < 4; ++m)
#pragma unroll
    for (int r = 0; r < 4; ++r) {
      int rowt = m*16 + lg*4 + r;
#pragma unroll
      for (int n = 0; n < 2; ++n) {
        int col = wc*32 + n*16 + lr;
        int idx = (rowt*16 + ((col>>3) ^ (rowt & 7)))*8 + (col & 7);
        S1[idx] = f2bs(acc1[m][n][r]);
        S2[idx] = f2bs(acc2[m][n][r]);
      }
    }
  __syncthreads();

  {
    const int row = t >> 2, cq = t & 3;
    if (row < nrows) {
      const short8* P1 = (const short8*)As;
      const short8* P2 = (const short8*)As2;
      const size_t gbase = (size_t)(r0 + row) * 128 + cq * 32;
#pragma unroll
      for (int cg = 0; cg < 4; ++cg) {
        int kg = cq * 4 + cg;
        short8 a1 = P1[row*16 + (kg ^ (row & 7))];
        short8 a2 = P2[row*16 + (kg ^ (row & 7))];
        uint4 ux = *(const uint4*)(gxb + gbase + cg*8);
        uint4 uy = *(const uint4*)(gyb + gbase + cg*8);
        unsigned xw[4] = {ux.x, ux.y, ux.z, ux.w};
        unsigned yw[4] = {uy.x, uy.y, uy.z, uy.w};
        unsigned ow[4];
#pragma unroll
        for (int p = 0; p < 4; ++p) {
          float g1l = __uint_as_float(xw[p] << 16);
          float g1h = __uint_as_float(xw[p] & 0xffff0000u);
          float g2l = __uint_as_float(yw[p] << 16);
          float g2h = __uint_as_float(yw[p] & 0xffff0000u);
          float sl = g1l * bf2f(a1[2*p])   + g2l * bf2f(a2[2*p]);
          float sh = g1h * bf2f(a1[2*p+1]) + g2h * bf2f(a2[2*p+1]);
          sl = fminf(fmaxf(sl, -15.f), 15.f);
          sh = fminf(fmaxf(sh, -15.f), 15.f);
          float el = __expf(2.f * sl), eh = __expf(2.f * sh);
          ow[p] = pk2((el - 1.f) / (el + 1.f), (eh - 1.f) / (eh + 1.f));
        }
        uint4 o; o.x = ow[0]; o.y = ow[1]; o.z = ow[2]; o.w = ow[3];
        *(uint4*)(gxb + gbase + cg*8) = o;
      }
    }
  }
}

// ---------------------------------------------------------------------------
// FUSED MLP (round-15 v1, best known): per 64-row tile: h1 = relu([x_in,xd,xg]
// @W1^T+b1) via 3 chunk stages, LDS restage -> h2 -> LDS restage -> out =
// h2@W3^T+b3+x_in. f32 LDS staging + coalesced epilogue.
// ---------------------------------------------------------------------------
__global__ __launch_bounds__(256)
void k_mlp(const float* __restrict__ xin, const __hip_bfloat16* __restrict__ xd,
           const __hip_bfloat16* __restrict__ xg,
           const uint4* __restrict__ W1f, const uint4* __restrict__ W2f,
           const uint4* __restrict__ W3f,
           const float* __restrict__ b1, const float* __restrict__ b2,
           const float* __restrict__ b3, float* __restrict__ out)
{
  const int b = blockIdx.y, r0 = blockIdx.x * 64, t = threadIdx.x;
  const int l = t & 63, w = t >> 6;
  const int lr = l & 15, lg = l >> 4;
  __shared__ uint4 LA[1024];     // A chunks; later f32 staging cols 0..63
  __shared__ uint4 LB[1024];     // h1/h2 frags; later f32 staging cols 64..127
  const int nrows = min(64, N_ - r0);
  const float* xinb = xin + (size_t)b * N_ * 128 + (size_t)r0 * 128;

  f32x4 acc[4][2];
#pragma unroll
  for (int m = 0; m < 4; ++m)
#pragma unroll
    for (int n = 0; n < 2; ++n) acc[m][n] = (f32x4)0.f;

  // ---- layer 1: 3 chunks ----
  for (int kc = 0; kc < 3; ++kc) {
    __syncthreads();
    if (kc == 0)      stg64r_f32(LA, xinb, nrows, t);
    else if (kc == 1) stg64r(LA, xd + (size_t)b * N_ * 128 + (size_t)r0 * 128, nrows, t);
    else              stg64r(LA, xg + (size_t)b * N_ * 128 + (size_t)r0 * 128, nrows, t);
    __syncthreads();
    mfma_pass64(LA, W1f + kc * 2048, w, lr, lg, acc);
  }
  // h1 = relu(acc + b1) -> LB frags
  {
    float bb[2] = { b1[w*32 + lr], b1[w*32 + 16 + lr] };
    short* Sh = (short*)LB;
#pragma unroll
    for (int m = 0; m < 4; ++m)
#pragma unroll
      for (int r = 0; r < 4; ++r) {
        int rowt = m*16 + lg*4 + r;
#pragma unroll
        for (int n = 0; n < 2; ++n) {
          int col = w*32 + n*16 + lr;
          float v = fmaxf(acc[m][n][r] + bb[n], 0.f);
          Sh[(rowt*16 + ((col>>3) ^ (rowt & 7)))*8 + (col & 7)] = f2bs(v);
        }
      }
  }
  __syncthreads();

  // ---- layer 2 ----
#pragma unroll
  for (int m = 0; m < 4; ++m)
#pragma unroll
    for (int n = 0; n < 2; ++n) acc[m][n] = (f32x4)0.f;
  mfma_pass64(LB, W2f, w, lr, lg, acc);
  __syncthreads();                         // all h1 reads done
  {
    float bb[2] = { b2[w*32 + lr], b2[w*32 + 16 + lr] };
    short* Sh = (short*)LB;
#pragma unroll
    for (int m = 0; m < 4; ++m)
#pragma unroll
      for (int r = 0; r < 4; ++r) {
        int rowt = m*16 + lg*4 + r;
#pragma unroll
        for (int n = 0; n < 2; ++n) {
          int col = w*32 + n*16 + lr;
          float v = fmaxf(acc[m][n][r] + bb[n], 0.f);
          Sh[(rowt*16 + ((col>>3) ^ (rowt & 7)))*8 + (col & 7)] = f2bs(v);
        }
      }
  }
  __syncthreads();

  // ---- layer 3 ----
#pragma unroll
  for (int m = 0; m < 4; ++m)
#pragma unroll
    for (int n = 0; n < 2; ++n) acc[m][n] = (f32x4)0.f;
  mfma_pass64(LB, W3f, w, lr, lg, acc);
  __syncthreads();                         // all h2 reads done

  // stage acc+b3 as f32: cols 0..63 -> LA, cols 64..127 -> LB
  {
    float bb[2] = { b3[w*32 + lr], b3[w*32 + 16 + lr] };
    float* F1 = (float*)LA;
    float* F2 = (float*)LB;
#pragma unroll
    for (int m = 0; m < 4; ++m)
#pragma unroll
      for (int r = 0; r < 4; ++r) {
        int rowt = m*16 + lg*4 + r;
#pragma unroll
        for (int n = 0; n < 2; ++n) {
          int col = w*32 + n*16 + lr;
          float v = acc[m][n][r] + bb[n];
          if (col < 64) F1[rowt*64 + col] = v;
          else          F2[rowt*64 + col - 64] = v;
        }
      }
  }
  __syncthreads();

  // coalesced epilogue: thread -> (row=t>>2, cols (t&3)*32..+31); + residual
  {
    const int row = t >> 2, cq = t & 3;
    if (row < nrows) {
      const float* Fs = (cq < 2) ? (const float*)LA : (const float*)LB;
      const float* fbase = Fs + row*64 + (cq & 1)*32;
      const float* xr = xinb + (size_t)row * 128 + cq * 32;
      float* orow = out + (size_t)b * N_ * 128 + (size_t)(r0 + row) * 128 + cq * 32;
#pragma unroll
      for (int j = 0; j < 8; ++j) {
        float4 s = ((const float4*)fbase)[j];
        float4 xv = ((const float4*)xr)[j];
        float4 o; o.x = s.x + xv.x; o.y = s.y + xv.y;
        o.z = s.z + xv.z; o.w = s.w + xv.w;
        ((float4*)orow)[j] = o;
      }
    }
  }
}

// ---------------------------------------------------------------------------
// SpMM: count -> hierarchical scan (blk/top/add) -> fill (packed recs) -> gather
// ---------------------------------------------------------------------------
__global__ void k_count(const int* __restrict__ rows, int* __restrict__ cnt)
{
  int b = blockIdx.y;
  int e = blockIdx.x * 256 + threadIdx.x;
  if (e < E_) atomicAdd(&cnt[b*N_ + rows[(size_t)b*E_ + e]], 1);
}

__global__ __launch_bounds__(256)
void k_scan_blk(const int* __restrict__ cnt, int* __restrict__ off,
                int* __restrict__ bsum)
{
  const int c = blockIdx.x, b = blockIdx.y, t = threadIdx.x;
  const int lane = t & 63, wid = t >> 6;
  __shared__ int wt[4];
  int i = c * 256 + t;
  int v = (i < N_) ? cnt[b*N_ + i] : 0;
  int x = v;
#pragma unroll
  for (int ofs = 1; ofs < 64; ofs <<= 1) {
    int y = __shfl_up(x, ofs, 64);
    if (lane >= ofs) x += y;
  }
  if (lane == 63) wt[wid] = x;
  __syncthreads();
  int wofs = 0;
  for (int wj = 0; wj < wid; ++wj) wofs += wt[wj];
  if (i < N_) off[b*(N_+1) + i] = wofs + x - v;
  if (t == 255) bsum[b*128 + c] = wofs + x;
}

__global__ __launch_bounds__(64)
void k_scan_top(int* __restrict__ bsum, int* __restrict__ off)
{
  const int b = blockIdx.x, t = threadIdx.x;
  int running = 0;
  for (int base = 0; base < 128; base += 64) {
    int i = base + t;
    int v = (i < NSCB) ? bsum[b*128 + i] : 0;
    int x = v;
#pragma unroll
    for (int ofs = 1; ofs < 64; ofs <<= 1) {
      int y = __shfl_up(x, ofs, 64);
      if (t >= ofs) x += y;
    }
    if (i < 128) bsum[b*128 + i] = running + x - v;
    running += __shfl(x, 63, 64);
  }
  if (t == 0) off[b*(N_+1) + N_] = running;
}

__global__ __launch_bounds__(256)
void k_scan_add(const int* __restrict__ bsum, int* __restrict__ off,
                int* __restrict__ pos)
{
  const int c = blockIdx.x, b = blockIdx.y;
  int i = c * 256 + (int)threadIdx.x;
  if (i < N_) {
    int o = off[b*(N_+1) + i] + bsum[b*128 + c];
    off[b*(N_+1) + i] = o;
    pos[b*N_ + i] = o;
  }
}

__global__ void k_fill(const int* __restrict__ rows, const int* __restrict__ cols,
                       const float* __restrict__ vx, const float* __restrict__ vy,
                       int* __restrict__ pos, uint4* __restrict__ prec)
{
  int b = blockIdx.y;
  int e = blockIdx.x * 256 + threadIdx.x;
  if (e < E_) {
    size_t be = (size_t)b*E_ + e;
    int r = rows[be];
    int p = atomicAdd(&pos[b*N_ + r], 1);
    if (p >= 0 && p < E_) {
      uint4 rec;
      rec.x = (unsigned)cols[be];
      rec.y = __float_as_uint(vx[be]);
      rec.z = __float_as_uint(vy[be]);
      rec.w = 0u;
      prec[(size_t)b*E_ + p] = rec;
    }
  }
}

// wave per row; quarter-wave per edge, unrolled 2x (8 edges in flight)
__global__ __launch_bounds__(256)
void k_gather(const __hip_bfloat16* __restrict__ xd, const uint4* __restrict__ prec,
              const int* __restrict__ off,
              __hip_bfloat16* __restrict__ gx, __hip_bfloat16* __restrict__ gy)
{
  const int b = blockIdx.y;
  const int row = (blockIdx.x * 256 + threadIdx.x) >> 6;
  const int lane = threadIdx.x & 63;
  const int q = lane >> 4, ql = lane & 15;
  if (row >= N_) return;
  const int s = off[b*(N_+1) + row], e = off[b*(N_+1) + row + 1];
  float ax[8], ay[8];
#pragma unroll
  for (int k = 0; k < 8; ++k) { ax[k] = 0.f; ay[k] = 0.f; }
  const __hip_bfloat16* xdb = xd + (size_t)b * N_ * P_;
  const uint4* pb = prec + (size_t)b * E_;

  for (int i = s; i < e; i += 8) {
    int idx0 = i + q, idx1 = i + 4 + q;
    bool v0 = idx0 < e, v1 = idx1 < e;
    uint4 rec0 = pb[v0 ? idx0 : (e - 1)];
    uint4 rec1 = pb[v1 ? idx1 : (e - 1)];
    float fx0 = v0 ? __uint_as_float(rec0.y) : 0.f;
    float fy0 = v0 ? __uint_as_float(rec0.z) : 0.f;
    float fx1 = v1 ? __uint_as_float(rec1.y) : 0.f;
    float fy1 = v1 ? __uint_as_float(rec1.z) : 0.f;
    uint4 va = *(const uint4*)(xdb + (size_t)rec0.x * P_ + ql * 8);
    uint4 vb = *(const uint4*)(xdb + (size_t)rec1.x * P_ + ql * 8);
    unsigned aw[4] = {va.x, va.y, va.z, va.w};
    unsigned bw[4] = {vb.x, vb.y, vb.z, vb.w};
#pragma unroll
    for (int p = 0; p < 4; ++p) {
      float a_lo = __uint_as_float(aw[p] << 16);
      float a_hi = __uint_as_float(aw[p] & 0xffff0000u);
      float b_lo = __uint_as_float(bw[p] << 16);
      float b_hi = __uint_as_float(bw[p] & 0xffff0000u);
      ax[2*p]   = fmaf(fx0, a_lo, ax[2*p]);   ax[2*p]   = fmaf(fx1, b_lo, ax[2*p]);
      ax[2*p+1] = fmaf(fx0, a_hi, ax[2*p+1]); ax[2*p+1] = fmaf(fx1, b_hi, ax[2*p+1]);
      ay[2*p]   = fmaf(fy0, a_lo, ay[2*p]);   ay[2*p]   = fmaf(fy1, b_lo, ay[2*p]);
      ay[2*p+1] = fmaf(fy0, a_hi, ay[2*p+1]); ay[2*p+1] = fmaf(fy1, b_hi, ay[2*p+1]);
    }
  }
#pragma unroll
  for (int k = 0; k < 8; ++k) {
    ax[k] += __shfl_xor(ax[k], 16, 64); ax[k] += __shfl_xor(ax[k], 32, 64);
    ay[k] += __shfl_xor(ay[k], 16, 64); ay[k] += __shfl_xor(ay[k], 32, 64);
  }
  if (lane < 16) {
    size_t o = (size_t)b * N_ * P_ + (size_t)row * P_ + ql * 8;
    uint4 ux, uy;
    ux.x = pk2(ax[0], ax[1]); ux.y = pk2(ax[2], ax[3]);
    ux.z = pk2(ax[4], ax[5]); ux.w = pk2(ax[6], ax[7]);
    uy.x = pk2(ay[0], ay[1]); uy.y = pk2(ay[2], ay[3]);
    uy.z = pk2(ay[4], ay[5]); uy.w = pk2(ay[6], ay[7]);
    *(uint4*)(gx + o) = ux;
    *(uint4*)(gy + o) = uy;
  }
}

// ---------------------------------------------------------------------------
extern "C" void kernel_launch(void* const* d_in, const int* in_sizes, int n_in,
                              void* d_out, int out_size, void* d_ws, size_t ws_size,
                              hipStream_t stream)
{
  const float* x_in  = (const float*)d_in[0];
  const float* areas = (const float*)d_in[1];
  const float* evals = (const float*)d_in[2];
  const float* evecs = (const float*)d_in[3];
  const float* gXv   = (const float*)d_in[4];
  const float* gYv   = (const float*)d_in[5];
  const int*   grows = (const int*)d_in[6];
  const int*   gcols = (const int*)d_in[7];
  const float* times = (const float*)d_in[8];
  const float* Bre   = (const float*)d_in[9];
  const float* Bim   = (const float*)d_in[10];
  const float* W1    = (const float*)d_in[11];
  const float* b1    = (const float*)d_in[12];
  const float* W2    = (const float*)d_in[13];
  const float* b2    = (const float*)d_in[14];
  const float* W3    = (const float*)d_in[15];
  const float* b3    = (const float*)d_in[16];

  float* ws = (float*)d_ws;
  // ws layout (float offsets) — d_out WRITE-ONLY:
  //   xd_bf [0, 5.12M) | part [6M, 11.18M) | gx/xg [12M, 17.12M) | gy [18M, 23.12M)
  //   scratch [24M, ~26.91M): prec | ipos | ioff | sspecT | WfRe | WfIm | bsum |
  //                           W1f | W2f | W3f | sTf
  __hip_bfloat16* xd_bf = (__hip_bfloat16*)ws;                  // x_diffuse bf16
  float*          part  = ws + 6000000;                         // fp32 partials
  __hip_bfloat16* gx_bf = (__hip_bfloat16*)(ws + 12000000);     // evT -> gx -> xg
  __hip_bfloat16* gy_bf = (__hip_bfloat16*)(ws + 18000000);     // xT  -> gy
  __hip_bfloat16* evT   = gx_bf;
  __hip_bfloat16* xT    = gy_bf;

  uint4* prec   = (uint4*)(ws + 24000000);          // B*E packed records
  int*   ipos   = (int*)(ws + 26560000);            // B*N counts/cursor
  int*   ioff   = ipos + B_*N_;                     // B*(N+1) offsets
  float* sspecT = ws + 26750000;                    // B*P*K fp32
  uint4* WfRe   = (uint4*)(ws + 26816000);          // 2048 uint4
  uint4* WfIm   = WfRe + 2048;                      // 2048 uint4
  int*   bsum   = (int*)(WfIm + 2048);              // B*128 block sums
  uint4* W1f    = (uint4*)(ws + 26834000);          // 3*2048 uint4
  uint4* W2f    = W1f + 6144;                       // 2048
  uint4* W3f    = W2f + 2048;                       // 2048
  uint4* sTf    = W3f + 2048;                       // B*2048
  float* out    = (float*)d_out;

  const int TN = (N_ + 63) / 64;    // 313 64-row tiles

  // spectral projection: transpose-prep -> MFMA split-K -> reduce+scale
  k_prep<<<dim3(TN, 4, B_), 256, 0, stream>>>(evecs, x_in, areas, evT, xT);
  k_wprep<<<dim3(8), 256, 0, stream>>>(Bre, Bim, WfRe, WfIm);
  k_wprep_mlp<<<dim3(40), 256, 0, stream>>>(W1, W2, W3, W1f, W2f, W3f);
  k_spec_mm<<<dim3(NCH_S, B_), 512, 0, stream>>>(evT, xT, part);
  k_spec_reduce<<<dim3(B_*K_*P_/256), 256, 0, stream>>>(part, evals, times, sspecT);
  k_wprep_spec<<<dim3(32), 256, 0, stream>>>(sspecT, sTf);
  // x_diffuse = evecs @ sspec (64-row tiles, per-batch W-frags) -> bf16
  k_unproj<<<dim3(TN, B_), 256, 0, stream>>>(evecs, sTf, xd_bf);
  // sparse gradient via counting sort (hierarchical scan, packed records)
  hipMemsetAsync(ipos, 0, (size_t)B_*N_*sizeof(int), stream);
  k_count<<<dim3(E_/256, B_), 256, 0, stream>>>(grows, ipos);
  k_scan_blk<<<dim3(NSCB, B_), 256, 0, stream>>>(ipos, ioff, bsum);
  k_scan_top<<<dim3(B_), 64, 0, stream>>>(bsum, ioff);
  k_scan_add<<<dim3(NSCB, B_), 256, 0, stream>>>(bsum, ioff, ipos);
  k_fill<<<dim3(E_/256, B_), 256, 0, stream>>>(grows, gcols, gXv, gYv, ipos, prec);
  k_gather<<<dim3(N_/4, B_), 256, 0, stream>>>(xd_bf, prec, ioff, gx_bf, gy_bf);
  // grad features (in place over gx -> xg)
  k_grad<<<dim3(TN, B_), 256, 0, stream>>>(WfRe, WfIm, gx_bf, gy_bf);
  // fused 3-layer MLP + residual -> d_out
  k_mlp<<<dim3(TN, B_), 256, 0, stream>>>(x_in, xd_bf, gx_bf, W1f, W2f, W3f,
                                          b1, b2, b3, out);
}